// Round 6
// baseline (394.667 us; speedup 1.0000x reference)
//
#include <hip/hip_runtime.h>

// CellList — all i<j pairs of N atoms, cutoff 5.2. Output: FLOAT32, flat,
// 7P elements, P = N(N-1)/2:
//   [0,P)    atom_pairs row i
//   [P,2P)   atom_pairs row j
//   [2P,3P)  in_cutoff (1.0/0.0)
//   [3P,6P)  diff [P,3] = (coords[i]-coords[j]) * in_cutoff
//   [6P,7P)  dist = in_cutoff ? ||coords[i]-coords[j]|| : 0
//
// Write-BW bound: 528 MB of f32 stores, inputs L1-resident.
// 8 pairs/thread, int64->f32 decode (no f64 sqrt), nontemporal vec4 stores
// (write-once stream > L3, avoid write-allocate pollution).

typedef float f32x4 __attribute__((ext_vector_type(4)));

static __device__ __forceinline__ void nt_store4(float* p, float a, float b,
                                                 float c, float d) {
    f32x4 v = {a, b, c, d};
    __builtin_nontemporal_store(v, reinterpret_cast<f32x4*>(p));
}

__global__ __launch_bounds__(256) void cell_pairs_f32(
    const int* __restrict__ species,
    const float* __restrict__ coords,
    float* __restrict__ out,
    int N, int P)
{
    int g  = blockIdx.x * blockDim.x + threadIdx.x;
    int p0 = g << 3;
    if (p0 >= P) return;

    // ---- decode (i,j) for first pair p0 ----
    // rows(i) = pairs before row i = i*(2N-1-i)/2
    // disc computed exactly in int64, then f32 sqrt; integer correction
    // loops make the result exact.
    const int twoNm1 = 2 * N - 1;
    long long disc_i = (long long)twoNm1 * (long long)twoNm1 - 8LL * (long long)p0;
    float sr = __fsqrt_rn((float)disc_i);
    int i = (int)(((float)twoNm1 - sr) * 0.5f);
    if (i < 0) i = 0;
    if (i > N - 2) i = N - 2;
    long long ri = ((long long)i * (long long)(twoNm1 - i)) >> 1;
    while (i < N - 2) {
        long long rn = ((long long)(i + 1) * (long long)(twoNm1 - (i + 1))) >> 1;
        if (rn <= (long long)p0) { ++i; ri = rn; } else break;
    }
    while (i > 0 && ri > (long long)p0) {
        --i; ri = ((long long)i * (long long)(twoNm1 - i)) >> 1;
    }
    int j = i + 1 + (int)((long long)p0 - ri);

    float cix = coords[3 * i + 0];
    float ciy = coords[3 * i + 1];
    float ciz = coords[3 * i + 2];
    int   si  = species[i];

    float iv[8], jv[8], cv[8], sv[8], dv[24];
    int nk = P - p0; if (nk > 8) nk = 8;

#pragma unroll 8
    for (int k = 0; k < 8; ++k) {
        if (k < nk) {
            if (j >= N) {
                ++i; j = i + 1;
                cix = coords[3 * i + 0];
                ciy = coords[3 * i + 1];
                ciz = coords[3 * i + 2];
                si  = species[i];
            }
            float dx = cix - coords[3 * j + 0];
            float dy = ciy - coords[3 * j + 1];
            float dz = ciz - coords[3 * j + 2];
            // numpy-exact f32: (dx*dx + dy*dy) + dz*dz, no FMA contraction
            float sq = __fadd_rn(__fadd_rn(__fmul_rn(dx, dx), __fmul_rn(dy, dy)),
                                 __fmul_rn(dz, dz));
            float d  = __fsqrt_rn(sq);
            bool inc = (d <= 5.2f) && (si != -1) && (species[j] != -1);
            float m  = inc ? 1.0f : 0.0f;

            iv[k] = (float)i;
            jv[k] = (float)j;
            cv[k] = m;
            sv[k] = __fmul_rn(d, m);
            dv[3 * k + 0] = __fmul_rn(dx, m);
            dv[3 * k + 1] = __fmul_rn(dy, m);
            dv[3 * k + 2] = __fmul_rn(dz, m);
            ++j;
        } else {
            iv[k] = 0.f; jv[k] = 0.f; cv[k] = 0.f; sv[k] = 0.f;
            dv[3 * k + 0] = 0.f; dv[3 * k + 1] = 0.f; dv[3 * k + 2] = 0.f;
        }
    }

    const size_t Ps = (size_t)P;
    if (nk == 8) {
        // P % 8 == 0 -> every base below is 16B-aligned
        float* o0 = out + (size_t)p0;
        nt_store4(o0,     iv[0], iv[1], iv[2], iv[3]);
        nt_store4(o0 + 4, iv[4], iv[5], iv[6], iv[7]);
        float* o1 = out + Ps + (size_t)p0;
        nt_store4(o1,     jv[0], jv[1], jv[2], jv[3]);
        nt_store4(o1 + 4, jv[4], jv[5], jv[6], jv[7]);
        float* o2 = out + 2 * Ps + (size_t)p0;
        nt_store4(o2,     cv[0], cv[1], cv[2], cv[3]);
        nt_store4(o2 + 4, cv[4], cv[5], cv[6], cv[7]);
        float* o6 = out + 6 * Ps + (size_t)p0;
        nt_store4(o6,     sv[0], sv[1], sv[2], sv[3]);
        nt_store4(o6 + 4, sv[4], sv[5], sv[6], sv[7]);
        float* od = out + 3 * Ps + 3 * (size_t)p0;
        nt_store4(od,      dv[0],  dv[1],  dv[2],  dv[3]);
        nt_store4(od + 4,  dv[4],  dv[5],  dv[6],  dv[7]);
        nt_store4(od + 8,  dv[8],  dv[9],  dv[10], dv[11]);
        nt_store4(od + 12, dv[12], dv[13], dv[14], dv[15]);
        nt_store4(od + 16, dv[16], dv[17], dv[18], dv[19]);
        nt_store4(od + 20, dv[20], dv[21], dv[22], dv[23]);
    } else {
        for (int k = 0; k < nk; ++k) {
            size_t p = (size_t)p0 + (size_t)k;
            out[p]                  = iv[k];
            out[Ps + p]             = jv[k];
            out[2 * Ps + p]         = cv[k];
            out[3 * Ps + 3 * p + 0] = dv[3 * k + 0];
            out[3 * Ps + 3 * p + 1] = dv[3 * k + 1];
            out[3 * Ps + 3 * p + 2] = dv[3 * k + 2];
            out[6 * Ps + p]         = sv[k];
        }
    }
}

extern "C" void kernel_launch(void* const* d_in, const int* in_sizes, int n_in,
                              void* d_out, int out_size, void* d_ws, size_t ws_size,
                              hipStream_t stream) {
    const int*   species = (const int*)d_in[0];
    const float* coords  = (const float*)d_in[1];
    int N = in_sizes[0];
    long long Pll = (long long)N * (long long)(N - 1) / 2;
    int P = (int)Pll;

    long long groups = (Pll + 7) >> 3;
    long long blocks = (groups + 255) / 256;
    cell_pairs_f32<<<dim3((unsigned)blocks), dim3(256), 0, stream>>>(
        species, coords, (float*)d_out, N, P);
}

// Round 7
// 154.961 us; speedup vs baseline: 2.5469x; 2.5469x over previous
//
#include <hip/hip_runtime.h>

// CellList — all i<j pairs of N atoms, cutoff 5.2. Output: FLOAT32, flat,
// 7P elements, P = N(N-1)/2:
//   [0,P)    atom_pairs row i
//   [P,2P)   atom_pairs row j
//   [2P,3P)  in_cutoff (1.0/0.0)
//   [3P,6P)  diff [P,3] = (coords[i]-coords[j]) * in_cutoff
//   [6P,7P)  dist = in_cutoff ? ||coords[i]-coords[j]|| : 0
//
// Write-BW bound: 528 MB of f32 stores, inputs L1-resident.
// 8 pairs/thread, int64->f32 sqrt decode. PLAIN float4 stores: round-6
// forensics showed nontemporal stores defeat L2 write-merging (WRITE_SIZE
// 528->988 MB, BW 5.2->2.4 TB/s). Let L2 aggregate full dirty lines.

__global__ __launch_bounds__(256) void cell_pairs_f32(
    const int* __restrict__ species,
    const float* __restrict__ coords,
    float* __restrict__ out,
    int N, int P)
{
    int g  = blockIdx.x * blockDim.x + threadIdx.x;
    int p0 = g << 3;
    if (p0 >= P) return;

    // ---- decode (i,j) for first pair p0 ----
    // rows(i) = pairs before row i = i*(2N-1-i)/2
    // disc exact in int64, f32 sqrt estimate, integer correction -> exact.
    const int twoNm1 = 2 * N - 1;
    long long disc_i = (long long)twoNm1 * (long long)twoNm1 - 8LL * (long long)p0;
    float sr = __fsqrt_rn((float)disc_i);
    int i = (int)(((float)twoNm1 - sr) * 0.5f);
    if (i < 0) i = 0;
    if (i > N - 2) i = N - 2;
    long long ri = ((long long)i * (long long)(twoNm1 - i)) >> 1;
    while (i < N - 2) {
        long long rn = ((long long)(i + 1) * (long long)(twoNm1 - (i + 1))) >> 1;
        if (rn <= (long long)p0) { ++i; ri = rn; } else break;
    }
    while (i > 0 && ri > (long long)p0) {
        --i; ri = ((long long)i * (long long)(twoNm1 - i)) >> 1;
    }
    int j = i + 1 + (int)((long long)p0 - ri);

    float cix = coords[3 * i + 0];
    float ciy = coords[3 * i + 1];
    float ciz = coords[3 * i + 2];
    int   si  = species[i];

    float iv[8], jv[8], cv[8], sv[8], dv[24];
    int nk = P - p0; if (nk > 8) nk = 8;

#pragma unroll 8
    for (int k = 0; k < 8; ++k) {
        if (k < nk) {
            if (j >= N) {
                ++i; j = i + 1;
                cix = coords[3 * i + 0];
                ciy = coords[3 * i + 1];
                ciz = coords[3 * i + 2];
                si  = species[i];
            }
            float dx = cix - coords[3 * j + 0];
            float dy = ciy - coords[3 * j + 1];
            float dz = ciz - coords[3 * j + 2];
            // numpy-exact f32: (dx*dx + dy*dy) + dz*dz, no FMA contraction
            float sq = __fadd_rn(__fadd_rn(__fmul_rn(dx, dx), __fmul_rn(dy, dy)),
                                 __fmul_rn(dz, dz));
            float d  = __fsqrt_rn(sq);
            bool inc = (d <= 5.2f) && (si != -1) && (species[j] != -1);
            float m  = inc ? 1.0f : 0.0f;

            iv[k] = (float)i;
            jv[k] = (float)j;
            cv[k] = m;
            sv[k] = __fmul_rn(d, m);
            dv[3 * k + 0] = __fmul_rn(dx, m);
            dv[3 * k + 1] = __fmul_rn(dy, m);
            dv[3 * k + 2] = __fmul_rn(dz, m);
            ++j;
        } else {
            iv[k] = 0.f; jv[k] = 0.f; cv[k] = 0.f; sv[k] = 0.f;
            dv[3 * k + 0] = 0.f; dv[3 * k + 1] = 0.f; dv[3 * k + 2] = 0.f;
        }
    }

    const size_t Ps = (size_t)P;
    if (nk == 8) {
        // P % 8 == 0 -> every base below is 16B-aligned
        float4* o0 = reinterpret_cast<float4*>(out + (size_t)p0);
        o0[0] = make_float4(iv[0], iv[1], iv[2], iv[3]);
        o0[1] = make_float4(iv[4], iv[5], iv[6], iv[7]);
        float4* o1 = reinterpret_cast<float4*>(out + Ps + (size_t)p0);
        o1[0] = make_float4(jv[0], jv[1], jv[2], jv[3]);
        o1[1] = make_float4(jv[4], jv[5], jv[6], jv[7]);
        float4* o2 = reinterpret_cast<float4*>(out + 2 * Ps + (size_t)p0);
        o2[0] = make_float4(cv[0], cv[1], cv[2], cv[3]);
        o2[1] = make_float4(cv[4], cv[5], cv[6], cv[7]);
        float4* o6 = reinterpret_cast<float4*>(out + 6 * Ps + (size_t)p0);
        o6[0] = make_float4(sv[0], sv[1], sv[2], sv[3]);
        o6[1] = make_float4(sv[4], sv[5], sv[6], sv[7]);
        float4* od = reinterpret_cast<float4*>(out + 3 * Ps + 3 * (size_t)p0);
        od[0] = make_float4(dv[0],  dv[1],  dv[2],  dv[3]);
        od[1] = make_float4(dv[4],  dv[5],  dv[6],  dv[7]);
        od[2] = make_float4(dv[8],  dv[9],  dv[10], dv[11]);
        od[3] = make_float4(dv[12], dv[13], dv[14], dv[15]);
        od[4] = make_float4(dv[16], dv[17], dv[18], dv[19]);
        od[5] = make_float4(dv[20], dv[21], dv[22], dv[23]);
    } else {
        for (int k = 0; k < nk; ++k) {
            size_t p = (size_t)p0 + (size_t)k;
            out[p]                  = iv[k];
            out[Ps + p]             = jv[k];
            out[2 * Ps + p]         = cv[k];
            out[3 * Ps + 3 * p + 0] = dv[3 * k + 0];
            out[3 * Ps + 3 * p + 1] = dv[3 * k + 1];
            out[3 * Ps + 3 * p + 2] = dv[3 * k + 2];
            out[6 * Ps + p]         = sv[k];
        }
    }
}

extern "C" void kernel_launch(void* const* d_in, const int* in_sizes, int n_in,
                              void* d_out, int out_size, void* d_ws, size_t ws_size,
                              hipStream_t stream) {
    const int*   species = (const int*)d_in[0];
    const float* coords  = (const float*)d_in[1];
    int N = in_sizes[0];
    long long Pll = (long long)N * (long long)(N - 1) / 2;
    int P = (int)Pll;

    long long groups = (Pll + 7) >> 3;
    long long blocks = (groups + 255) / 256;
    cell_pairs_f32<<<dim3((unsigned)blocks), dim3(256), 0, stream>>>(
        species, coords, (float*)d_out, N, P);
}

// Round 8
// 101.089 us; speedup vs baseline: 3.9041x; 1.5329x over previous
//
#include <hip/hip_runtime.h>

// CellList — all i<j pairs of N atoms, cutoff 5.2. Output: FLOAT32, flat,
// 7P elements, P = N(N-1)/2:
//   [0,P)    atom_pairs row i
//   [P,2P)   atom_pairs row j
//   [2P,3P)  in_cutoff (1.0/0.0)
//   [3P,6P)  diff [P,3] = (coords[i]-coords[j]) * in_cutoff
//   [6P,7P)  dist = in_cutoff ? ||coords[i]-coords[j]|| : 0
//
// Store-BW bound (528 MB). Every global store instruction must be a DENSE
// 16B/lane wave transaction:
//  - r6 forensics: nontemporal stores defeat L2 write-merge (WRITE 988 MB).
//  - r7 forensics: 8 pairs/thread makes narrow streams 2-way interleaved
//    (lane stride 32B, 16B stores) -> 102->155 us.
// This version: 4 pairs/thread (narrow streams dense), diff stream made
// dense via 12 KB LDS transpose per 1024-pair block.

__global__ __launch_bounds__(256) void cell_pairs_f32(
    const int* __restrict__ species,
    const float* __restrict__ coords,
    float* __restrict__ out,
    int N, int P)
{
    __shared__ float ldsd[3072];            // 1024 pairs x 3 floats = 12 KB

    const int t   = threadIdx.x;
    const int blk = blockIdx.x << 10;       // 1024 pairs per block
    if (blk >= P) return;
    const bool full = (blk + 1024 <= P);
    const int p0 = blk + (t << 2);

    // ---- decode (i,j) for first pair p0 (valid when p0 < P) ----
    // rows(i) = i*(2N-1-i)/2; exact int64 disc, f32 sqrt, int correction.
    const int twoNm1 = 2 * N - 1;
    int i = 0, j = 1;
    if (p0 < P) {
        long long disc_i = (long long)twoNm1 * (long long)twoNm1 - 8LL * (long long)p0;
        float sr = __fsqrt_rn((float)disc_i);
        i = (int)(((float)twoNm1 - sr) * 0.5f);
        if (i < 0) i = 0;
        if (i > N - 2) i = N - 2;
        long long ri = ((long long)i * (long long)(twoNm1 - i)) >> 1;
        while (i < N - 2) {
            long long rn = ((long long)(i + 1) * (long long)(twoNm1 - (i + 1))) >> 1;
            if (rn <= (long long)p0) { ++i; ri = rn; } else break;
        }
        while (i > 0 && ri > (long long)p0) {
            --i; ri = ((long long)i * (long long)(twoNm1 - i)) >> 1;
        }
        j = i + 1 + (int)((long long)p0 - ri);
    }

    if (full) {
        float cix = coords[3 * i + 0];
        float ciy = coords[3 * i + 1];
        float ciz = coords[3 * i + 2];
        int   si  = species[i];

        float iv[4], jv[4], cv[4], sv[4], dv[12];
#pragma unroll 4
        for (int k = 0; k < 4; ++k) {
            if (j >= N) {
                ++i; j = i + 1;
                cix = coords[3 * i + 0];
                ciy = coords[3 * i + 1];
                ciz = coords[3 * i + 2];
                si  = species[i];
            }
            float dx = cix - coords[3 * j + 0];
            float dy = ciy - coords[3 * j + 1];
            float dz = ciz - coords[3 * j + 2];
            // numpy-exact f32: (dx*dx + dy*dy) + dz*dz, no FMA contraction
            float sq = __fadd_rn(__fadd_rn(__fmul_rn(dx, dx), __fmul_rn(dy, dy)),
                                 __fmul_rn(dz, dz));
            float d  = __fsqrt_rn(sq);
            bool inc = (d <= 5.2f) && (si != -1) && (species[j] != -1);
            float m  = inc ? 1.0f : 0.0f;

            iv[k] = (float)i;
            jv[k] = (float)j;
            cv[k] = m;
            sv[k] = __fmul_rn(d, m);
            dv[3 * k + 0] = __fmul_rn(dx, m);
            dv[3 * k + 1] = __fmul_rn(dy, m);
            dv[3 * k + 2] = __fmul_rn(dz, m);
            ++j;
        }

        // diff -> LDS (dense: 48B/lane, ds_write_b128 x3)
        float4* lw = reinterpret_cast<float4*>(&ldsd[12 * t]);
        lw[0] = make_float4(dv[0], dv[1], dv[2],  dv[3]);
        lw[1] = make_float4(dv[4], dv[5], dv[6],  dv[7]);
        lw[2] = make_float4(dv[8], dv[9], dv[10], dv[11]);

        // narrow streams direct (dense: 16B/lane stride 16B)
        const size_t Ps = (size_t)P;
        *reinterpret_cast<float4*>(out + (size_t)p0)
            = make_float4(iv[0], iv[1], iv[2], iv[3]);
        *reinterpret_cast<float4*>(out + Ps + (size_t)p0)
            = make_float4(jv[0], jv[1], jv[2], jv[3]);
        *reinterpret_cast<float4*>(out + 2 * Ps + (size_t)p0)
            = make_float4(cv[0], cv[1], cv[2], cv[3]);
        *reinterpret_cast<float4*>(out + 6 * Ps + (size_t)p0)
            = make_float4(sv[0], sv[1], sv[2], sv[3]);

        __syncthreads();

        // diff writeback: 3 dense chunks of 1024 floats
        const float4* lr = reinterpret_cast<const float4*>(ldsd);
        float4 d0 = lr[t];
        float4 d1 = lr[t + 256];
        float4 d2 = lr[t + 512];
        float* gd = out + 3 * Ps + 3 * (size_t)blk;
        reinterpret_cast<float4*>(gd)[t]        = d0;
        reinterpret_cast<float4*>(gd + 1024)[t] = d1;
        reinterpret_cast<float4*>(gd + 2048)[t] = d2;
    } else {
        // partial tail block (not hit when P % 1024 == 0): scalar, no barrier
        const size_t Ps = (size_t)P;
        for (int k = 0; k < 4; ++k) {
            int p = p0 + k;
            if (p >= P) break;
            if (j >= N) { ++i; j = i + 1; }
            float dx = coords[3 * i + 0] - coords[3 * j + 0];
            float dy = coords[3 * i + 1] - coords[3 * j + 1];
            float dz = coords[3 * i + 2] - coords[3 * j + 2];
            float sq = __fadd_rn(__fadd_rn(__fmul_rn(dx, dx), __fmul_rn(dy, dy)),
                                 __fmul_rn(dz, dz));
            float d  = __fsqrt_rn(sq);
            bool inc = (d <= 5.2f) && (species[i] != -1) && (species[j] != -1);
            float m  = inc ? 1.0f : 0.0f;
            size_t pp = (size_t)p;
            out[pp]                  = (float)i;
            out[Ps + pp]             = (float)j;
            out[2 * Ps + pp]         = m;
            out[3 * Ps + 3 * pp + 0] = __fmul_rn(dx, m);
            out[3 * Ps + 3 * pp + 1] = __fmul_rn(dy, m);
            out[3 * Ps + 3 * pp + 2] = __fmul_rn(dz, m);
            out[6 * Ps + pp]         = __fmul_rn(d, m);
            ++j;
        }
    }
}

extern "C" void kernel_launch(void* const* d_in, const int* in_sizes, int n_in,
                              void* d_out, int out_size, void* d_ws, size_t ws_size,
                              hipStream_t stream) {
    const int*   species = (const int*)d_in[0];
    const float* coords  = (const float*)d_in[1];
    int N = in_sizes[0];
    long long Pll = (long long)N * (long long)(N - 1) / 2;
    int P = (int)Pll;

    long long blocks = (Pll + 1023) >> 10;   // 1024 pairs per block
    cell_pairs_f32<<<dim3((unsigned)blocks), dim3(256), 0, stream>>>(
        species, coords, (float*)d_out, N, P);
}